// Round 20
// baseline (109.139 us; speedup 1.0000x reference)
//
#include <hip/hip_runtime.h>
#include <hip/hip_bf16.h>
#include <cstdint>

#define S_LEN 2048
#define D_MODEL 1024
#define NHEAD 16
#define DHEAD 64
#define BATCH 2

typedef __attribute__((ext_vector_type(4))) __bf16 bf16x4v;
typedef __attribute__((ext_vector_type(8))) __bf16 bf16x8v;
typedef __attribute__((ext_vector_type(16))) float f32x16;
typedef const __attribute__((address_space(1))) uint32_t gu32;
typedef __attribute__((address_space(3))) uint32_t lu32;

#define QSCALE 0.18033688011112042f  // 1/sqrt(64) * log2(e), folded into Q-proj

// k-dim storage permute: swap bits 2,3 of the element index so each MFMA
// fragment is 16 CONTIGUOUS bytes -> single ds_read_b128.
__device__ __forceinline__ int perm4(int gidx) {
    return (gidx & ~3) | ((gidx & 1) << 1) | ((gidx >> 1) & 1);
}
__device__ __forceinline__ int permk(int k) {
    return (k & ~12) | ((k & 4) << 1) | ((k & 8) >> 1);
}

// ---------------- prep: query fp32 -> bf16 (k-permuted) + all weight transposes ----------
__global__ __launch_bounds__(256) void prep_all(
    const float* __restrict__ query,
    const float* __restrict__ Wq, const float* __restrict__ Wo,
    const float* __restrict__ Wk, const float* __restrict__ Wv,
    __hip_bfloat16* __restrict__ Qin,
    __hip_bfloat16* __restrict__ Wqt, __hip_bfloat16* __restrict__ Wohit,
    __hip_bfloat16* __restrict__ Wkvt)
{
    const int bid = blockIdx.x;
    const int tid = threadIdx.x;
    if (bid < 4096) {
        const int idx = bid * 256 + tid;
        const float4 v = reinterpret_cast<const float4*>(query)[idx];
        bf16x4v o = { (__bf16)v.x, (__bf16)v.y, (__bf16)v.z, (__bf16)v.w };
        *reinterpret_cast<bf16x4v*>(Qin + (size_t)perm4(idx) * 4) = o;
        return;
    }
    const int b2 = bid - 4096;
    const int bx = b2 & 31, by = (b2 >> 5) & 31, z = b2 >> 10;
    const float* W;
    __hip_bfloat16* T;
    int wcols, trowoff;
    if (z == 0)      { W = Wq; T = Wqt;   wcols = 1024; trowoff = 0; }
    else if (z == 1) { W = Wo; T = Wohit; wcols = 1024; trowoff = 0; }
    else if (z == 2) { W = Wk; T = Wkvt;  wcols = 64;   trowoff = 0; }
    else             { W = Wv; T = Wkvt;  wcols = 64;   trowoff = 64; }
    if (bx * 32 >= wcols) return;

    __shared__ float ld[32][33];
    {
        const int rr = tid >> 3;
        const int c4 = (tid & 7) * 4;
        const float4 v = *reinterpret_cast<const float4*>(
            &W[(size_t)(by * 32 + rr) * wcols + bx * 32 + c4]);
        ld[rr][c4 + 0] = v.x; ld[rr][c4 + 1] = v.y;
        ld[rr][c4 + 2] = v.z; ld[rr][c4 + 3] = v.w;
    }
    __syncthreads();
    const int jj = tid & 31;
#pragma unroll
    for (int ii = 0; ii < 4; ++ii) {
        const int rr = (tid >> 5) * 4 + ii;
        T[(size_t)(trowoff + bx * 32 + rr) * 1024 + by * 32 + permk(jj)] =
            __float2bfloat16(ld[jj][rr]);
    }
}

// ---------------- fused: proj_kv (blocks 0..63) + Q-proj GEMM (blocks 64..319) ----------
__global__ __launch_bounds__(512, 1) void qproj_projkv(
    const __hip_bfloat16* __restrict__ Qin,   // [4096][1024] k-permuted
    const __hip_bfloat16* __restrict__ Wqt,   // [1024][1024] k-permuted
    const float* __restrict__ bq,
    __hip_bfloat16* __restrict__ Qbf,         // out, d-permuted, pre-scaled
    const float* __restrict__ value,          // [4096][1024] fp32
    const __hip_bfloat16* __restrict__ Wkvt,  // [128][1024] k-permuted
    const float* __restrict__ bk, const float* __restrict__ bv,
    __hip_bfloat16* __restrict__ Kb,          // [4096][64] d-permuted
    __hip_bfloat16* __restrict__ Vt)          // [B][64][2048] s-permuted
{
    __shared__ __align__(16) char lds[131072];
    const int bid = blockIdx.x;
    const int tid = threadIdx.x;

    if (bid < 64) {
        // ---------------- proj_kv path ----------------
        const int unit = tid >> 8;
        const int ltid = tid & 255;
        const int w = ltid >> 6, lane = ltid & 63;
        const int g = lane >> 5, r = lane & 31;
        const int rowBase = bid * 64 + unit * 32;
        char* ub = lds + unit * 65536;

        auto stage = [&](int buf, int t) {
            const int kk = t * 64;
            char* dst = ub + buf * 24576;
#pragma unroll
            for (int j = 0; j < 2; ++j) {
                const int oo  = j * 4096 + ltid * 16;
                const int row = oo >> 8;
                const int cb  = (oo & 255) ^ ((row & 7) << 4);
                __builtin_amdgcn_global_load_lds(
                    (gu32*)((const char*)value + (size_t)(rowBase + row) * 4096 + kk * 4 + cb),
                    (lu32*)(dst + oo), 16, 0, 0);
            }
#pragma unroll
            for (int j = 0; j < 4; ++j) {
                const int oo  = j * 4096 + ltid * 16;
                const int row = oo >> 7;
                const int cb  = (oo & 127) ^ ((row & 7) << 4);
                __builtin_amdgcn_global_load_lds(
                    (gu32*)((const char*)Wkvt + (size_t)row * 2048 + kk * 2 + cb),
                    (lu32*)(dst + 8192 + oo), 16, 0, 0);
            }
        };

        f32x16 acc;
#pragma unroll
        for (int i = 0; i < 16; ++i) acc[i] = 0.f;

        stage(0, 0);

        for (int t = 0; t < 16; ++t) {
            const int cur = t & 1;
            if (t < 15) {
                stage(cur ^ 1, t + 1);
                asm volatile("s_waitcnt vmcnt(6)" ::: "memory");
            } else {
                asm volatile("s_waitcnt vmcnt(0)" ::: "memory");
            }
            asm volatile("s_barrier" ::: "memory");

            const char* ab = ub + cur * 24576;
            const char* bb = ab + 8192;

#pragma unroll
            for (int ks = 0; ks < 4; ++ks) {
                const int sza = (r & 7) << 4;
                const char* pa = ab + r * 256;
                const float4 x0 = *reinterpret_cast<const float4*>(
                    pa + ((ks * 64 + g * 16) ^ sza));
                const float4 x1 = *reinterpret_cast<const float4*>(
                    pa + ((ks * 64 + 32 + g * 16) ^ sza));
                bf16x8v af = {(__bf16)x0.x, (__bf16)x0.y, (__bf16)x0.z, (__bf16)x0.w,
                              (__bf16)x1.x, (__bf16)x1.y, (__bf16)x1.z, (__bf16)x1.w};
                bf16x8v bf = *reinterpret_cast<const bf16x8v*>(
                    bb + (w * 32 + r) * 128 + ((ks * 32 + g * 16) ^ sza));
                acc = __builtin_amdgcn_mfma_f32_32x32x16_bf16(af, bf, acc, 0, 0, 0);
            }
            asm volatile("s_barrier" ::: "memory");
        }

        __syncthreads();
        float* ep = reinterpret_cast<float*>(ub);   // [32][132]
#pragma unroll
        for (int reg = 0; reg < 16; ++reg) {
            const int m = (reg & 3) + 8 * (reg >> 2) + 4 * g;
            ep[m * 132 + w * 32 + r] = acc[reg];
        }
        __syncthreads();

        {   // K: rows 32 x cols 64, d-granules permuted
            const int m  = ltid >> 3;
            const int g0 = (ltid & 7) * 2;
#pragma unroll
            for (int j = 0; j < 2; ++j) {
                const int gsrc = g0 + j;
                bf16x4v o4;
#pragma unroll
                for (int i2 = 0; i2 < 4; ++i2)
                    o4[i2] = (__bf16)(ep[m * 132 + gsrc * 4 + i2] + bk[gsrc * 4 + i2]);
                *reinterpret_cast<bf16x4v*>(
                    Kb + (size_t)(rowBase + m) * 64 + perm4(gsrc) * 4) = o4;
            }
        }
        {   // V^T: s-granules permuted
            const int vc = ltid >> 2;
            const int g0 = (ltid & 3) * 2;
            const int batch = rowBase >> 11;
            const float bvv = bv[vc];
#pragma unroll
            for (int j = 0; j < 2; ++j) {
                const int gsrc = g0 + j;
                bf16x4v o4;
#pragma unroll
                for (int i2 = 0; i2 < 4; ++i2)
                    o4[i2] = (__bf16)(ep[(gsrc * 4 + i2) * 132 + 64 + vc] + bvv);
                *reinterpret_cast<bf16x4v*>(
                    Vt + ((size_t)(batch * 64 + vc)) * 2048 + (rowBase & 2047) + perm4(gsrc) * 4) = o4;
            }
        }
        return;
    }

    // ---------------- Q-proj GEMM path (bf16 A, 4-buf deep pipe) ----------------
    const int lin = bid - 64;
    const int w = tid >> 6, lane = tid & 63;
    const int g = lane >> 5, r = lane & 31;
    const int wr = w >> 2, wc = w & 3;
    const int swz = (lin & 7) * 32 + (lin >> 3);
    const int rowBase = (swz >> 3) * 128;
    const int colBase = (swz & 7) * 128;

    auto stage = [&](int buf, int t) {
        const int kk = t * 64;
        char* dst = lds + buf * 32768;
#pragma unroll
        for (int j = 0; j < 2; ++j) {
            const int oo  = j * 8192 + tid * 16;
            const int row = oo >> 7;
            const int cb  = (oo & 127) ^ ((row & 7) << 4);
            __builtin_amdgcn_global_load_lds(
                (gu32*)((const char*)Qin + (size_t)(rowBase + row) * 2048 + kk * 2 + cb),
                (lu32*)(dst + oo), 16, 0, 0);
            __builtin_amdgcn_global_load_lds(
                (gu32*)((const char*)Wqt + (size_t)(colBase + row) * 2048 + kk * 2 + cb),
                (lu32*)(dst + 16384 + oo), 16, 0, 0);
        }
    };

    f32x16 acc[2];
#pragma unroll
    for (int i = 0; i < 16; ++i) { acc[0][i] = 0.f; acc[1][i] = 0.f; }

    stage(0, 0); stage(1, 1); stage(2, 2);

    for (int t = 0; t < 16; ++t) {
        if (t <= 13)      { asm volatile("s_waitcnt vmcnt(8)" ::: "memory"); }
        else if (t == 14) { asm volatile("s_waitcnt vmcnt(4)" ::: "memory"); }
        else              { asm volatile("s_waitcnt vmcnt(0)" ::: "memory"); }
        asm volatile("s_barrier" ::: "memory");

        if (t + 3 < 16) stage((t + 3) & 3, t + 3);

        const char* ahb = lds + (t & 3) * 32768;
        const char* bb  = ahb + 16384;

        __builtin_amdgcn_s_setprio(1);
#pragma unroll
        for (int ks = 0; ks < 4; ++ks) {
            bf16x8v a[2], bfr;
#pragma unroll
            for (int mt = 0; mt < 2; ++mt) {
                const int rowl = wr * 64 + mt * 32 + r;
                const int sz = (rowl & 7) << 4;
                a[mt] = *reinterpret_cast<const bf16x8v*>(
                    ahb + rowl * 128 + ((ks * 32 + g * 16) ^ sz));
            }
            {
                const int rowl = wc * 32 + r;
                const int sz = (rowl & 7) << 4;
                bfr = *reinterpret_cast<const bf16x8v*>(
                    bb + rowl * 128 + ((ks * 32 + g * 16) ^ sz));
            }
#pragma unroll
            for (int mt = 0; mt < 2; ++mt)
                acc[mt] = __builtin_amdgcn_mfma_f32_32x32x16_bf16(a[mt], bfr, acc[mt], 0, 0, 0);
        }
        __builtin_amdgcn_s_setprio(0);
    }

    const int col = colBase + wc * 32 + r;
    const int colp = permk(col);
    const float bvv = bq[col];
#pragma unroll
    for (int mt = 0; mt < 2; ++mt)
#pragma unroll
        for (int reg = 0; reg < 16; ++reg) {
            const int row = rowBase + wr * 64 + mt * 32 + (reg & 3) + 8 * (reg >> 2) + 4 * g;
            Qbf[(size_t)row * 1024 + colp] =
                (__hip_bfloat16)((acc[mt][reg] + bvv) * QSCALE);
        }
}

// ---------------- O-proj GEMM: out = A@Wohit^T + bo (single pass, 4-buf deep pipe) ------
__global__ __launch_bounds__(512, 1) void gemm_oproj(
    const __hip_bfloat16* __restrict__ A,     // [4096][1024] bf16, k-permuted
    const __hip_bfloat16* __restrict__ Bhi,
    const float* __restrict__ bias, float* __restrict__ C)
{
    __shared__ __align__(16) char lds[131072];

    const int tid = threadIdx.x;
    const int w = tid >> 6, lane = tid & 63;
    const int g = lane >> 5, r = lane & 31;
    const int wr = w >> 2, wc = w & 3;
    const int lin = blockIdx.y * 8 + blockIdx.x;
    const int swz = (lin & 7) * 32 + (lin >> 3);
    const int rowBase = (swz >> 3) * 128;
    const int colBase = (swz & 7) * 128;

    auto stage = [&](int buf, int t) {
        const int kk = t * 64;
        char* dst = lds + buf * 32768;
#pragma unroll
        for (int j = 0; j < 2; ++j) {
            const int oo  = j * 8192 + tid * 16;
            const int row = oo >> 7;
            const int cb  = (oo & 127) ^ ((row & 7) << 4);
            __builtin_amdgcn_global_load_lds(
                (gu32*)((const char*)A + (size_t)(rowBase + row) * 2048 + kk * 2 + cb),
                (lu32*)(dst + oo), 16, 0, 0);
            __builtin_amdgcn_global_load_lds(
                (gu32*)((const char*)Bhi + (size_t)(colBase + row) * 2048 + kk * 2 + cb),
                (lu32*)(dst + 16384 + oo), 16, 0, 0);
        }
    };

    f32x16 acc[2];
#pragma unroll
    for (int i = 0; i < 16; ++i) { acc[0][i] = 0.f; acc[1][i] = 0.f; }

    stage(0, 0); stage(1, 1); stage(2, 2);

    for (int t = 0; t < 16; ++t) {
        if (t <= 13)      { asm volatile("s_waitcnt vmcnt(8)" ::: "memory"); }
        else if (t == 14) { asm volatile("s_waitcnt vmcnt(4)" ::: "memory"); }
        else              { asm volatile("s_waitcnt vmcnt(0)" ::: "memory"); }
        asm volatile("s_barrier" ::: "memory");

        if (t + 3 < 16) stage((t + 3) & 3, t + 3);

        const char* ahb = lds + (t & 3) * 32768;
        const char* bb  = ahb + 16384;

        __builtin_amdgcn_s_setprio(1);
#pragma unroll
        for (int ks = 0; ks < 4; ++ks) {
            bf16x8v a[2], bfr;
#pragma unroll
            for (int mt = 0; mt < 2; ++mt) {
                const int rowl = wr * 64 + mt * 32 + r;
                const int sz = (rowl & 7) << 4;
                a[mt] = *reinterpret_cast<const bf16x8v*>(
                    ahb + rowl * 128 + ((ks * 32 + g * 16) ^ sz));
            }
            {
                const int rowl = wc * 32 + r;
                const int sz = (rowl & 7) << 4;
                bfr = *reinterpret_cast<const bf16x8v*>(
                    bb + rowl * 128 + ((ks * 32 + g * 16) ^ sz));
            }
#pragma unroll
            for (int mt = 0; mt < 2; ++mt)
                acc[mt] = __builtin_amdgcn_mfma_f32_32x32x16_bf16(a[mt], bfr, acc[mt], 0, 0, 0);
        }
        __builtin_amdgcn_s_setprio(0);
    }

    const int col = colBase + wc * 32 + r;
    const float bvv = bias[col];
#pragma unroll
    for (int mt = 0; mt < 2; ++mt)
#pragma unroll
        for (int reg = 0; reg < 16; ++reg) {
            const int row = rowBase + wr * 64 + mt * 32 + (reg & 3) + 8 * (reg >> 2) + 4 * g;
            C[(size_t)row * 1024 + col] = acc[mt][reg] + bvv;
        }
}

// ---------------- MFMA flash MQA attention: 64 q-rows/wave, 1 block/CU ----------------
// Each wave owns TWO 32-row q-subtiles. K/V fragments (koff/voff are
// wave-independent and subtile-independent) are read ONCE per (mt,ks) and feed
// 2 MFMAs -> ds_read count per q-row HALVES vs round-19 (LDS was the largest
// non-VALU pipe). 1 wave/SIMD: VGPR budget 512, ~300 used (launch_bounds(256,1)).
// Same depth-3 pipeline, one barrier/tile, counted vmcnt. No setprio (r18).
// A output aliases Qbf IN PLACE (per-block stripe, same geometry).
__global__ __launch_bounds__(256, 1) void mqa_attn_mfma(
    const __hip_bfloat16* __restrict__ Qbf,   // [B*S][1024], pre-scaled, d-permuted
    const __hip_bfloat16* __restrict__ Kbf,   // [B*S][64], d-permuted
    const __hip_bfloat16* __restrict__ Vt,    // [B][64][S], s-permuted
    __hip_bfloat16* __restrict__ Ahi)         // [B*S][1024], d-permuted out (alias Qbf)
{
    __shared__ __align__(16) char lds[65536];

    const int bh = blockIdx.y, b = bh >> 4, h = bh & 15;
    const int qt = blockIdx.x;                 // 0..7, 256 q-rows per block
    const int tid = threadIdx.x;
    const int w = tid >> 6, lane = tid & 63;
    const int g = lane >> 5, q = lane & 31;

    bf16x8v qf[2][4];
#pragma unroll
    for (int su = 0; su < 2; ++su) {
        const __hip_bfloat16* qp =
            Qbf + ((size_t)(b * S_LEN + qt * 256 + w * 64 + su * 32 + q)) * D_MODEL + h * DHEAD;
#pragma unroll
        for (int ks = 0; ks < 4; ++ks)
            qf[su][ks] = *reinterpret_cast<const bf16x8v*>(qp + ks * 16 + g * 8);
    }

    const bf16x8v onesf = {(__bf16)1.f, (__bf16)1.f, (__bf16)1.f, (__bf16)1.f,
                           (__bf16)1.f, (__bf16)1.f, (__bf16)1.f, (__bf16)1.f};
    f32x16 fzero;
#pragma unroll
    for (int i = 0; i < 16; ++i) fzero[i] = 0.f;

    int koff[2][4], voff[2][4];
#pragma unroll
    for (int mt = 0; mt < 2; ++mt) {
        const int key = mt * 32 + q;
        const int swzk = (key & 7) << 4;
#pragma unroll
        for (int ks = 0; ks < 4; ++ks) {
            koff[mt][ks] = key * 128 + ((ks * 32 + g * 16) ^ swzk);
            voff[mt][ks] = 8192 + key * 128 + ((ks * 32 + g * 16) ^ swzk);
        }
    }

    const char* kbase = (const char*)Kbf + (size_t)b * S_LEN * DHEAD * 2;
    const char* vbase = (const char*)Vt + (size_t)b * DHEAD * S_LEN * 2;

    auto stage = [&](int buf, int t0) {
        char* dst = lds + buf * 16384;
#pragma unroll
        for (int j = 0; j < 2; ++j) {
            const int oo = j * 4096 + tid * 16;
            const int rr = oo >> 7;
            const int cc = (oo & 127) ^ ((rr & 7) << 4);
            __builtin_amdgcn_global_load_lds(
                (gu32*)(kbase + (size_t)(t0 + rr) * 128 + cc),
                (lu32*)(dst + oo), 16, 0, 0);
            __builtin_amdgcn_global_load_lds(
                (gu32*)(vbase + (size_t)rr * (S_LEN * 2) + t0 * 2 + cc),
                (lu32*)(dst + 8192 + oo), 16, 0, 0);
        }
    };

    f32x16 oacc[2][2], oacc_l[2];
#pragma unroll
    for (int i = 0; i < 16; ++i) {
        oacc[0][0][i] = 0.f; oacc[0][1][i] = 0.f;
        oacc[1][0][i] = 0.f; oacc[1][1][i] = 0.f;
        oacc_l[0][i] = 0.f;  oacc_l[1][i] = 0.f;
    }

    // QK^T: each K-frag read ONCE, used by both q-subtiles.
    auto qkt = [&](f32x16 (&SD)[2][2], int buf) {
        const char* kb_ = lds + buf * 16384;
#pragma unroll
        for (int mt = 0; mt < 2; ++mt) {
            bf16x8v af0 = *reinterpret_cast<const bf16x8v*>(kb_ + koff[mt][0]);
            SD[0][mt] = __builtin_amdgcn_mfma_f32_32x32x16_bf16(af0, qf[0][0], fzero, 0, 0, 0);
            SD[1][mt] = __builtin_amdgcn_mfma_f32_32x32x16_bf16(af0, qf[1][0], fzero, 0, 0, 0);
#pragma unroll
            for (int ks = 1; ks < 4; ++ks) {
                bf16x8v af = *reinterpret_cast<const bf16x8v*>(kb_ + koff[mt][ks]);
                SD[0][mt] = __builtin_amdgcn_mfma_f32_32x32x16_bf16(af, qf[0][ks], SD[0][mt], 0, 0, 0);
                SD[1][mt] = __builtin_amdgcn_mfma_f32_32x32x16_bf16(af, qf[1][ks], SD[1][mt], 0, 0, 0);
            }
        }
    };

    // softmax + PV: each V-frag read ONCE, used by both q-subtiles.
    auto smpv = [&](f32x16 (&SD)[2][2], int buf) {
#pragma unroll
        for (int su = 0; su < 2; ++su)
#pragma unroll
            for (int mt = 0; mt < 2; ++mt)
#pragma unroll
                for (int r2 = 0; r2 < 16; ++r2)
                    SD[su][mt][r2] = exp2f(SD[su][mt][r2]);

        bf16x8v pf[2][4];
#pragma unroll
        for (int su = 0; su < 2; ++su)
#pragma unroll
            for (int ks = 0; ks < 4; ++ks)
#pragma unroll
                for (int e2 = 0; e2 < 8; ++e2)
                    pf[su][ks][e2] = (__bf16)SD[su][ks >> 1][(ks & 1) * 8 + e2];

        const char* kb_ = lds + buf * 16384;
#pragma unroll
        for (int mt = 0; mt < 2; ++mt) {
#pragma unroll
            for (int ks = 0; ks < 4; ++ks) {
                bf16x8v af = *reinterpret_cast<const bf16x8v*>(kb_ + voff[mt][ks]);
                oacc[0][mt] = __builtin_amdgcn_mfma_f32_32x32x16_bf16(af, pf[0][ks], oacc[0][mt], 0, 0, 0);
                oacc[1][mt] = __builtin_amdgcn_mfma_f32_32x32x16_bf16(af, pf[1][ks], oacc[1][mt], 0, 0, 0);
            }
        }
#pragma unroll
        for (int su = 0; su < 2; ++su)
#pragma unroll
            for (int ks = 0; ks < 4; ++ks)
                oacc_l[su] = __builtin_amdgcn_mfma_f32_32x32x16_bf16(onesf, pf[su][ks], oacc_l[su], 0, 0, 0);
    };

    f32x16 sA[2][2], sB[2][2];

    stage(0, 0); stage(1, 64); stage(2, 128);
    asm volatile("s_waitcnt vmcnt(8)" ::: "memory");
    asm volatile("s_barrier" ::: "memory");
    qkt(sA, 0);

#define BODY(SB_, TILE_, BQ_, BP_, CUR, NXT, VMCSTR, DOSTAGE)               \
    {                                                                        \
        asm volatile("s_waitcnt vmcnt(" VMCSTR ")" ::: "memory");            \
        asm volatile("s_barrier" ::: "memory");                              \
        if (DOSTAGE) stage(SB_, TILE_);                                      \
        qkt(NXT, BQ_);                                                       \
        smpv(CUR, BP_);                                                      \
    }

    for (int ib = 0; ib < 7; ++ib) {
        const int t4 = ib * 4;
        BODY(3, (t4 + 3) * 64, 1, 0, sA, sB, "4", true);
        BODY(0, (t4 + 4) * 64, 2, 1, sB, sA, "4", true);
        BODY(1, (t4 + 5) * 64, 3, 2, sA, sB, "4", true);
        BODY(2, (t4 + 6) * 64, 0, 3, sB, sA, "4", true);
    }
    BODY(3, 31 * 64, 1, 0, sA, sB, "4", true);
    BODY(0, 0,       2, 1, sB, sA, "4", false);
    BODY(0, 0,       3, 2, sA, sB, "0", false);
#undef BODY
    smpv(sB, 3);

    // epilogue: two passes (one per q-subtile), 33KB LDS each.
    const float inv[2] = { 1.f / oacc_l[0][0], 1.f / oacc_l[1][0] };
    const size_t obase = (size_t)(b * S_LEN + qt * 256) * D_MODEL + h * DHEAD;

#pragma unroll
    for (int su = 0; su < 2; ++su) {
        __syncthreads();
        {
            float* ep = reinterpret_cast<float*>(lds) + w * 2080;
#pragma unroll
            for (int mt = 0; mt < 2; ++mt)
#pragma unroll
                for (int r = 0; r < 16; ++r) {
                    const int d = mt * 32 + (r & 3) + ((r >> 2) * 8) + g * 4;
                    ep[q * 65 + d] = oacc[su][mt][r] * inv[su];
                }
        }
        __syncthreads();

        for (int i = tid; i < 128 * 16; i += 256) {
            const int rloc = i >> 4, G = i & 15;
            const int wv = rloc >> 5, rw = rloc & 31;
            const float* src = reinterpret_cast<float*>(lds) + wv * 2080 + rw * 65 + G * 4;
            const size_t o = obase + (size_t)(wv * 64 + su * 32 + rw) * D_MODEL + perm4(G) * 4;
            bf16x4v hv;
#pragma unroll
            for (int j = 0; j < 4; ++j) hv[j] = (__bf16)src[j];
            *reinterpret_cast<bf16x4v*>(Ahi + o) = hv;
        }
    }
}

// ---------------- launch ----------------
extern "C" void kernel_launch(void* const* d_in, const int* in_sizes, int n_in,
                              void* d_out, int out_size, void* d_ws, size_t ws_size,
                              hipStream_t stream)
{
    const float* query = (const float*)d_in[0];
    const float* value = (const float*)d_in[1];
    const float* Wq    = (const float*)d_in[2];
    const float* bq    = (const float*)d_in[3];
    const float* Wk    = (const float*)d_in[4];
    const float* bk    = (const float*)d_in[5];
    const float* Wv    = (const float*)d_in[6];
    const float* bv    = (const float*)d_in[7];
    const float* Wo    = (const float*)d_in[8];
    const float* bo    = (const float*)d_in[9];
    float* out = (float*)d_out;

    char* ws = (char*)d_ws;
    const size_t MB = 1024 * 1024;
    // 21.25 MB layout (proven-safe bound):
    //   [0,8)    Qin
    //   [8,16)   Qbf -> A (attention output aliases in place, same geometry)
    //   [16,18)  Wqt
    //   [18,18.5) Kbf   [18.5,19) Vt
    //   [19,21)  Wohit  [21,21.25) Wkvt
    __hip_bfloat16* Qin   = (__hip_bfloat16*)(ws);
    __hip_bfloat16* Qbf   = (__hip_bfloat16*)(ws + 8 * MB);
    __hip_bfloat16* Abuf  = (__hip_bfloat16*)(ws + 8 * MB);
    __hip_bfloat16* Wqt   = (__hip_bfloat16*)(ws + 16 * MB);
    __hip_bfloat16* Kbf   = (__hip_bfloat16*)(ws + 18 * MB);
    __hip_bfloat16* Vt    = (__hip_bfloat16*)(ws + 18 * MB + 524288);
    __hip_bfloat16* Wohit = (__hip_bfloat16*)(ws + 19 * MB);
    __hip_bfloat16* Wkvt  = (__hip_bfloat16*)(ws + 21 * MB);

    prep_all<<<dim3(8192), dim3(256), 0, stream>>>(
        query, Wq, Wo, Wk, Wv, Qin, Wqt, Wohit, Wkvt);

    qproj_projkv<<<dim3(320), dim3(512), 0, stream>>>(
        Qin, Wqt, bq, Qbf, value, Wkvt, bk, bv, Kbf, Vt);

    mqa_attn_mfma<<<dim3(S_LEN / 256, BATCH * NHEAD), dim3(256), 0, stream>>>(
        Qbf, Kbf, Vt, Abuf);

    gemm_oproj<<<dim3(8, 32), dim3(512), 0, stream>>>(
        Abuf, Wohit, bo, out);
}

// Round 21
// 100.517 us; speedup vs baseline: 1.0858x; 1.0858x over previous
//
#include <hip/hip_runtime.h>
#include <hip/hip_bf16.h>
#include <cstdint>

#define S_LEN 2048
#define D_MODEL 1024
#define NHEAD 16
#define DHEAD 64
#define BATCH 2

typedef __attribute__((ext_vector_type(4))) __bf16 bf16x4v;
typedef __attribute__((ext_vector_type(8))) __bf16 bf16x8v;
typedef __attribute__((ext_vector_type(16))) float f32x16;
typedef const __attribute__((address_space(1))) uint32_t gu32;
typedef __attribute__((address_space(3))) uint32_t lu32;

#define QSCALE 0.18033688011112042f  // 1/sqrt(64) * log2(e), folded into Q-proj

// k-dim storage permute: swap bits 2,3 of the element index so each MFMA
// fragment is 16 CONTIGUOUS bytes -> single ds_read_b128.
__device__ __forceinline__ int perm4(int gidx) {
    return (gidx & ~3) | ((gidx & 1) << 1) | ((gidx >> 1) & 1);
}
__device__ __forceinline__ int permk(int k) {
    return (k & ~12) | ((k & 4) << 1) | ((k & 8) >> 1);
}

// ---------------- prep: query fp32 -> bf16 (k-permuted) + all weight transposes ----------
__global__ __launch_bounds__(256) void prep_all(
    const float* __restrict__ query,
    const float* __restrict__ Wq, const float* __restrict__ Wo,
    const float* __restrict__ Wk, const float* __restrict__ Wv,
    __hip_bfloat16* __restrict__ Qin,
    __hip_bfloat16* __restrict__ Wqt, __hip_bfloat16* __restrict__ Wohit,
    __hip_bfloat16* __restrict__ Wkvt)
{
    const int bid = blockIdx.x;
    const int tid = threadIdx.x;
    if (bid < 4096) {
        const int idx = bid * 256 + tid;
        const float4 v = reinterpret_cast<const float4*>(query)[idx];
        bf16x4v o = { (__bf16)v.x, (__bf16)v.y, (__bf16)v.z, (__bf16)v.w };
        *reinterpret_cast<bf16x4v*>(Qin + (size_t)perm4(idx) * 4) = o;
        return;
    }
    const int b2 = bid - 4096;
    const int bx = b2 & 31, by = (b2 >> 5) & 31, z = b2 >> 10;
    const float* W;
    __hip_bfloat16* T;
    int wcols, trowoff;
    if (z == 0)      { W = Wq; T = Wqt;   wcols = 1024; trowoff = 0; }
    else if (z == 1) { W = Wo; T = Wohit; wcols = 1024; trowoff = 0; }
    else if (z == 2) { W = Wk; T = Wkvt;  wcols = 64;   trowoff = 0; }
    else             { W = Wv; T = Wkvt;  wcols = 64;   trowoff = 64; }
    if (bx * 32 >= wcols) return;

    __shared__ float ld[32][33];
    {   // float4 loads: 8 threads/row x 32 rows
        const int rr = tid >> 3;
        const int c4 = (tid & 7) * 4;
        const float4 v = *reinterpret_cast<const float4*>(
            &W[(size_t)(by * 32 + rr) * wcols + bx * 32 + c4]);
        ld[rr][c4 + 0] = v.x; ld[rr][c4 + 1] = v.y;
        ld[rr][c4 + 2] = v.z; ld[rr][c4 + 3] = v.w;
    }
    __syncthreads();
    const int jj = tid & 31;
#pragma unroll
    for (int ii = 0; ii < 4; ++ii) {
        const int rr = (tid >> 5) * 4 + ii;
        T[(size_t)(trowoff + bx * 32 + rr) * 1024 + by * 32 + permk(jj)] =
            __float2bfloat16(ld[jj][rr]);
    }
}

// ---------------- fused: proj_kv (blocks 0..63) + Q-proj GEMM (blocks 64..319) ----------
__global__ __launch_bounds__(512, 1) void qproj_projkv(
    const __hip_bfloat16* __restrict__ Qin,   // [4096][1024] k-permuted
    const __hip_bfloat16* __restrict__ Wqt,   // [1024][1024] k-permuted
    const float* __restrict__ bq,
    __hip_bfloat16* __restrict__ Qbf,         // out, d-permuted, pre-scaled
    const float* __restrict__ value,          // [4096][1024] fp32
    const __hip_bfloat16* __restrict__ Wkvt,  // [128][1024] k-permuted
    const float* __restrict__ bk, const float* __restrict__ bv,
    __hip_bfloat16* __restrict__ Kb,          // [4096][64] d-permuted
    __hip_bfloat16* __restrict__ Vt)          // [B][64][2048] s-permuted
{
    __shared__ __align__(16) char lds[131072];
    const int bid = blockIdx.x;
    const int tid = threadIdx.x;

    if (bid < 64) {
        // ---------------- proj_kv path ----------------
        const int unit = tid >> 8;
        const int ltid = tid & 255;
        const int w = ltid >> 6, lane = ltid & 63;
        const int g = lane >> 5, r = lane & 31;
        const int rowBase = bid * 64 + unit * 32;
        char* ub = lds + unit * 65536;

        auto stage = [&](int buf, int t) {
            const int kk = t * 64;
            char* dst = ub + buf * 24576;
#pragma unroll
            for (int j = 0; j < 2; ++j) {
                const int oo  = j * 4096 + ltid * 16;
                const int row = oo >> 8;
                const int cb  = (oo & 255) ^ ((row & 7) << 4);
                __builtin_amdgcn_global_load_lds(
                    (gu32*)((const char*)value + (size_t)(rowBase + row) * 4096 + kk * 4 + cb),
                    (lu32*)(dst + oo), 16, 0, 0);
            }
#pragma unroll
            for (int j = 0; j < 4; ++j) {
                const int oo  = j * 4096 + ltid * 16;
                const int row = oo >> 7;
                const int cb  = (oo & 127) ^ ((row & 7) << 4);
                __builtin_amdgcn_global_load_lds(
                    (gu32*)((const char*)Wkvt + (size_t)row * 2048 + kk * 2 + cb),
                    (lu32*)(dst + 8192 + oo), 16, 0, 0);
            }
        };

        f32x16 acc;
#pragma unroll
        for (int i = 0; i < 16; ++i) acc[i] = 0.f;

        stage(0, 0);

        for (int t = 0; t < 16; ++t) {
            const int cur = t & 1;
            if (t < 15) {
                stage(cur ^ 1, t + 1);
                asm volatile("s_waitcnt vmcnt(6)" ::: "memory");
            } else {
                asm volatile("s_waitcnt vmcnt(0)" ::: "memory");
            }
            asm volatile("s_barrier" ::: "memory");

            const char* ab = ub + cur * 24576;
            const char* bb = ab + 8192;

#pragma unroll
            for (int ks = 0; ks < 4; ++ks) {
                const int sza = (r & 7) << 4;
                const char* pa = ab + r * 256;
                const float4 x0 = *reinterpret_cast<const float4*>(
                    pa + ((ks * 64 + g * 16) ^ sza));
                const float4 x1 = *reinterpret_cast<const float4*>(
                    pa + ((ks * 64 + 32 + g * 16) ^ sza));
                bf16x8v af = {(__bf16)x0.x, (__bf16)x0.y, (__bf16)x0.z, (__bf16)x0.w,
                              (__bf16)x1.x, (__bf16)x1.y, (__bf16)x1.z, (__bf16)x1.w};
                bf16x8v bf = *reinterpret_cast<const bf16x8v*>(
                    bb + (w * 32 + r) * 128 + ((ks * 32 + g * 16) ^ sza));
                acc = __builtin_amdgcn_mfma_f32_32x32x16_bf16(af, bf, acc, 0, 0, 0);
            }
            asm volatile("s_barrier" ::: "memory");
        }

        __syncthreads();
        float* ep = reinterpret_cast<float*>(ub);   // [32][132]
#pragma unroll
        for (int reg = 0; reg < 16; ++reg) {
            const int m = (reg & 3) + 8 * (reg >> 2) + 4 * g;
            ep[m * 132 + w * 32 + r] = acc[reg];
        }
        __syncthreads();

        {   // K: rows 32 x cols 64, d-granules permuted
            const int m  = ltid >> 3;
            const int g0 = (ltid & 7) * 2;
#pragma unroll
            for (int j = 0; j < 2; ++j) {
                const int gsrc = g0 + j;
                bf16x4v o4;
#pragma unroll
                for (int i2 = 0; i2 < 4; ++i2)
                    o4[i2] = (__bf16)(ep[m * 132 + gsrc * 4 + i2] + bk[gsrc * 4 + i2]);
                *reinterpret_cast<bf16x4v*>(
                    Kb + (size_t)(rowBase + m) * 64 + perm4(gsrc) * 4) = o4;
            }
        }
        {   // V^T: s-granules permuted
            const int vc = ltid >> 2;
            const int g0 = (ltid & 3) * 2;
            const int batch = rowBase >> 11;
            const float bvv = bv[vc];
#pragma unroll
            for (int j = 0; j < 2; ++j) {
                const int gsrc = g0 + j;
                bf16x4v o4;
#pragma unroll
                for (int i2 = 0; i2 < 4; ++i2)
                    o4[i2] = (__bf16)(ep[(gsrc * 4 + i2) * 132 + 64 + vc] + bvv);
                *reinterpret_cast<bf16x4v*>(
                    Vt + ((size_t)(batch * 64 + vc)) * 2048 + (rowBase & 2047) + perm4(gsrc) * 4) = o4;
            }
        }
        return;
    }

    // ---------------- Q-proj GEMM path (bf16 A, 4-buf deep pipe) ----------------
    const int lin = bid - 64;
    const int w = tid >> 6, lane = tid & 63;
    const int g = lane >> 5, r = lane & 31;
    const int wr = w >> 2, wc = w & 3;
    const int swz = (lin & 7) * 32 + (lin >> 3);
    const int rowBase = (swz >> 3) * 128;
    const int colBase = (swz & 7) * 128;

    auto stage = [&](int buf, int t) {
        const int kk = t * 64;
        char* dst = lds + buf * 32768;
#pragma unroll
        for (int j = 0; j < 2; ++j) {
            const int oo  = j * 8192 + tid * 16;
            const int row = oo >> 7;
            const int cb  = (oo & 127) ^ ((row & 7) << 4);
            __builtin_amdgcn_global_load_lds(
                (gu32*)((const char*)Qin + (size_t)(rowBase + row) * 2048 + kk * 2 + cb),
                (lu32*)(dst + oo), 16, 0, 0);
            __builtin_amdgcn_global_load_lds(
                (gu32*)((const char*)Wqt + (size_t)(colBase + row) * 2048 + kk * 2 + cb),
                (lu32*)(dst + 16384 + oo), 16, 0, 0);
        }
    };

    f32x16 acc[2];
#pragma unroll
    for (int i = 0; i < 16; ++i) { acc[0][i] = 0.f; acc[1][i] = 0.f; }

    stage(0, 0); stage(1, 1); stage(2, 2);

    for (int t = 0; t < 16; ++t) {
        if (t <= 13)      { asm volatile("s_waitcnt vmcnt(8)" ::: "memory"); }
        else if (t == 14) { asm volatile("s_waitcnt vmcnt(4)" ::: "memory"); }
        else              { asm volatile("s_waitcnt vmcnt(0)" ::: "memory"); }
        asm volatile("s_barrier" ::: "memory");

        if (t + 3 < 16) stage((t + 3) & 3, t + 3);

        const char* ahb = lds + (t & 3) * 32768;
        const char* bb  = ahb + 16384;

        __builtin_amdgcn_s_setprio(1);
#pragma unroll
        for (int ks = 0; ks < 4; ++ks) {
            bf16x8v a[2], bfr;
#pragma unroll
            for (int mt = 0; mt < 2; ++mt) {
                const int rowl = wr * 64 + mt * 32 + r;
                const int sz = (rowl & 7) << 4;
                a[mt] = *reinterpret_cast<const bf16x8v*>(
                    ahb + rowl * 128 + ((ks * 32 + g * 16) ^ sz));
            }
            {
                const int rowl = wc * 32 + r;
                const int sz = (rowl & 7) << 4;
                bfr = *reinterpret_cast<const bf16x8v*>(
                    bb + rowl * 128 + ((ks * 32 + g * 16) ^ sz));
            }
#pragma unroll
            for (int mt = 0; mt < 2; ++mt)
                acc[mt] = __builtin_amdgcn_mfma_f32_32x32x16_bf16(a[mt], bfr, acc[mt], 0, 0, 0);
        }
        __builtin_amdgcn_s_setprio(0);
    }

    const int col = colBase + wc * 32 + r;
    const int colp = permk(col);
    const float bvv = bq[col];
#pragma unroll
    for (int mt = 0; mt < 2; ++mt)
#pragma unroll
        for (int reg = 0; reg < 16; ++reg) {
            const int row = rowBase + wr * 64 + mt * 32 + (reg & 3) + 8 * (reg >> 2) + 4 * g;
            Qbf[(size_t)row * 1024 + colp] =
                (__hip_bfloat16)((acc[mt][reg] + bvv) * QSCALE);
        }
}

// ---------------- O-proj GEMM: out = A@Wohit^T + bo (single pass, 4-buf deep pipe) ------
__global__ __launch_bounds__(512, 1) void gemm_oproj(
    const __hip_bfloat16* __restrict__ A,     // [4096][1024] bf16, k-permuted
    const __hip_bfloat16* __restrict__ Bhi,
    const float* __restrict__ bias, float* __restrict__ C)
{
    __shared__ __align__(16) char lds[131072];

    const int tid = threadIdx.x;
    const int w = tid >> 6, lane = tid & 63;
    const int g = lane >> 5, r = lane & 31;
    const int wr = w >> 2, wc = w & 3;
    const int lin = blockIdx.y * 8 + blockIdx.x;
    const int swz = (lin & 7) * 32 + (lin >> 3);
    const int rowBase = (swz >> 3) * 128;
    const int colBase = (swz & 7) * 128;

    auto stage = [&](int buf, int t) {
        const int kk = t * 64;
        char* dst = lds + buf * 32768;
#pragma unroll
        for (int j = 0; j < 2; ++j) {
            const int oo  = j * 8192 + tid * 16;
            const int row = oo >> 7;
            const int cb  = (oo & 127) ^ ((row & 7) << 4);
            __builtin_amdgcn_global_load_lds(
                (gu32*)((const char*)A + (size_t)(rowBase + row) * 2048 + kk * 2 + cb),
                (lu32*)(dst + oo), 16, 0, 0);
            __builtin_amdgcn_global_load_lds(
                (gu32*)((const char*)Bhi + (size_t)(colBase + row) * 2048 + kk * 2 + cb),
                (lu32*)(dst + 16384 + oo), 16, 0, 0);
        }
    };

    f32x16 acc[2];
#pragma unroll
    for (int i = 0; i < 16; ++i) { acc[0][i] = 0.f; acc[1][i] = 0.f; }

    stage(0, 0); stage(1, 1); stage(2, 2);

    for (int t = 0; t < 16; ++t) {
        if (t <= 13)      { asm volatile("s_waitcnt vmcnt(8)" ::: "memory"); }
        else if (t == 14) { asm volatile("s_waitcnt vmcnt(4)" ::: "memory"); }
        else              { asm volatile("s_waitcnt vmcnt(0)" ::: "memory"); }
        asm volatile("s_barrier" ::: "memory");

        if (t + 3 < 16) stage((t + 3) & 3, t + 3);

        const char* ahb = lds + (t & 3) * 32768;
        const char* bb  = ahb + 16384;

        __builtin_amdgcn_s_setprio(1);
#pragma unroll
        for (int ks = 0; ks < 4; ++ks) {
            bf16x8v a[2], bfr;
#pragma unroll
            for (int mt = 0; mt < 2; ++mt) {
                const int rowl = wr * 64 + mt * 32 + r;
                const int sz = (rowl & 7) << 4;
                a[mt] = *reinterpret_cast<const bf16x8v*>(
                    ahb + rowl * 128 + ((ks * 32 + g * 16) ^ sz));
            }
            {
                const int rowl = wc * 32 + r;
                const int sz = (rowl & 7) << 4;
                bfr = *reinterpret_cast<const bf16x8v*>(
                    bb + rowl * 128 + ((ks * 32 + g * 16) ^ sz));
            }
#pragma unroll
            for (int mt = 0; mt < 2; ++mt)
                acc[mt] = __builtin_amdgcn_mfma_f32_32x32x16_bf16(a[mt], bfr, acc[mt], 0, 0, 0);
        }
        __builtin_amdgcn_s_setprio(0);
    }

    const int col = colBase + wc * 32 + r;
    const float bvv = bias[col];
#pragma unroll
    for (int mt = 0; mt < 2; ++mt)
#pragma unroll
        for (int reg = 0; reg < 16; ++reg) {
            const int row = rowBase + wr * 64 + mt * 32 + (reg & 3) + 8 * (reg >> 2) + 4 * g;
            C[(size_t)row * 1024 + col] = acc[mt][reg] + bvv;
        }
}

// ---------------- MFMA flash MQA attention (round-17/19 proven structure) ----------------
// 32 q-rows/wave, 4 waves, 2 blocks/CU (proven ILP/TLP sweet spot; r20's
// 64-row variant lost more to 1-wave/SIMD latency exposure than it saved in
// LDS traffic). No setprio (r18). sm inside smpv after qkt (r18). l via
// ones-MFMA. No max tracking. Q pre-scaled by QSCALE.
// A output aliases Qbf IN PLACE (per-block stripe, same geometry).
__global__ __launch_bounds__(256, 2) void mqa_attn_mfma(
    const __hip_bfloat16* __restrict__ Qbf,   // [B*S][1024], pre-scaled, d-permuted
    const __hip_bfloat16* __restrict__ Kbf,   // [B*S][64], d-permuted
    const __hip_bfloat16* __restrict__ Vt,    // [B][64][S], s-permuted
    __hip_bfloat16* __restrict__ Ahi)         // [B*S][1024], d-permuted out (alias Qbf)
{
    __shared__ __align__(16) char lds[65536];

    const int bh = blockIdx.y, b = bh >> 4, h = bh & 15;
    const int qt = blockIdx.x;
    const int tid = threadIdx.x;
    const int w = tid >> 6, lane = tid & 63;
    const int g = lane >> 5, q = lane & 31;

    bf16x8v qf[4];
    {
        const __hip_bfloat16* qp =
            Qbf + ((size_t)(b * S_LEN + qt * 128 + w * 32 + q)) * D_MODEL + h * DHEAD;
#pragma unroll
        for (int ks = 0; ks < 4; ++ks)
            qf[ks] = *reinterpret_cast<const bf16x8v*>(qp + ks * 16 + g * 8);
    }

    const bf16x8v onesf = {(__bf16)1.f, (__bf16)1.f, (__bf16)1.f, (__bf16)1.f,
                           (__bf16)1.f, (__bf16)1.f, (__bf16)1.f, (__bf16)1.f};
    f32x16 fzero;
#pragma unroll
    for (int i = 0; i < 16; ++i) fzero[i] = 0.f;

    int koff[2][4], voff[2][4];
#pragma unroll
    for (int mt = 0; mt < 2; ++mt) {
        const int key = mt * 32 + q;
        const int swzk = (key & 7) << 4;
#pragma unroll
        for (int ks = 0; ks < 4; ++ks) {
            koff[mt][ks] = key * 128 + ((ks * 32 + g * 16) ^ swzk);
            voff[mt][ks] = 8192 + key * 128 + ((ks * 32 + g * 16) ^ swzk);
        }
    }

    const char* kbase = (const char*)Kbf + (size_t)b * S_LEN * DHEAD * 2;
    const char* vbase = (const char*)Vt + (size_t)b * DHEAD * S_LEN * 2;

    auto stage = [&](int buf, int t0) {
        char* dst = lds + buf * 16384;
#pragma unroll
        for (int j = 0; j < 2; ++j) {
            const int oo = j * 4096 + tid * 16;
            const int rr = oo >> 7;
            const int cc = (oo & 127) ^ ((rr & 7) << 4);
            __builtin_amdgcn_global_load_lds(
                (gu32*)(kbase + (size_t)(t0 + rr) * 128 + cc),
                (lu32*)(dst + oo), 16, 0, 0);
            __builtin_amdgcn_global_load_lds(
                (gu32*)(vbase + (size_t)rr * (S_LEN * 2) + t0 * 2 + cc),
                (lu32*)(dst + 8192 + oo), 16, 0, 0);
        }
    };

    f32x16 oacc[2], oacc_l;
#pragma unroll
    for (int i = 0; i < 16; ++i) { oacc[0][i] = 0.f; oacc[1][i] = 0.f; oacc_l[i] = 0.f; }

    auto qkt = [&](f32x16 (&SD)[2], int buf) {
        const char* kb_ = lds + buf * 16384;
#pragma unroll
        for (int mt = 0; mt < 2; ++mt) {
            bf16x8v af0 = *reinterpret_cast<const bf16x8v*>(kb_ + koff[mt][0]);
            SD[mt] = __builtin_amdgcn_mfma_f32_32x32x16_bf16(af0, qf[0], fzero, 0, 0, 0);
#pragma unroll
            for (int ks = 1; ks < 4; ++ks) {
                bf16x8v af = *reinterpret_cast<const bf16x8v*>(kb_ + koff[mt][ks]);
                SD[mt] = __builtin_amdgcn_mfma_f32_32x32x16_bf16(af, qf[ks], SD[mt], 0, 0, 0);
            }
        }
    };

    auto smpv = [&](f32x16 (&SD)[2], int buf) {
#pragma unroll
        for (int mt = 0; mt < 2; ++mt)
#pragma unroll
            for (int r2 = 0; r2 < 16; ++r2)
                SD[mt][r2] = exp2f(SD[mt][r2]);

        bf16x8v pf[4];
#pragma unroll
        for (int ks = 0; ks < 4; ++ks)
#pragma unroll
            for (int e2 = 0; e2 < 8; ++e2)
                pf[ks][e2] = (__bf16)SD[ks >> 1][(ks & 1) * 8 + e2];

        const char* kb_ = lds + buf * 16384;
#pragma unroll
        for (int mt = 0; mt < 2; ++mt) {
#pragma unroll
            for (int ks = 0; ks < 4; ++ks) {
                bf16x8v af = *reinterpret_cast<const bf16x8v*>(kb_ + voff[mt][ks]);
                oacc[mt] = __builtin_amdgcn_mfma_f32_32x32x16_bf16(af, pf[ks], oacc[mt], 0, 0, 0);
            }
        }
#pragma unroll
        for (int ks = 0; ks < 4; ++ks)
            oacc_l = __builtin_amdgcn_mfma_f32_32x32x16_bf16(onesf, pf[ks], oacc_l, 0, 0, 0);
    };

    f32x16 sA[2], sB[2];

    stage(0, 0); stage(1, 64); stage(2, 128);
    asm volatile("s_waitcnt vmcnt(8)" ::: "memory");
    asm volatile("s_barrier" ::: "memory");
    qkt(sA, 0);

#define BODY(SB_, TILE_, BQ_, BP_, CUR, NXT, VMCSTR, DOSTAGE)               \
    {                                                                        \
        asm volatile("s_waitcnt vmcnt(" VMCSTR ")" ::: "memory");            \
        asm volatile("s_barrier" ::: "memory");                              \
        if (DOSTAGE) stage(SB_, TILE_);                                      \
        qkt(NXT, BQ_);                                                       \
        smpv(CUR, BP_);                                                      \
    }

    for (int ib = 0; ib < 7; ++ib) {
        const int t4 = ib * 4;
        BODY(3, (t4 + 3) * 64, 1, 0, sA, sB, "4", true);
        BODY(0, (t4 + 4) * 64, 2, 1, sB, sA, "4", true);
        BODY(1, (t4 + 5) * 64, 3, 2, sA, sB, "4", true);
        BODY(2, (t4 + 6) * 64, 0, 3, sB, sA, "4", true);
    }
    BODY(3, 31 * 64, 1, 0, sA, sB, "4", true);
    BODY(0, 0,       2, 1, sB, sA, "4", false);
    BODY(0, 0,       3, 2, sA, sB, "0", false);
#undef BODY
    smpv(sB, 3);

    // epilogue: normalize, transpose via LDS (pad 65), d-permuted bf16 store
    const float inv = 1.f / oacc_l[0];
    __syncthreads();
    {
        float* ep = reinterpret_cast<float*>(lds) + w * 2080;
#pragma unroll
        for (int mt = 0; mt < 2; ++mt)
#pragma unroll
            for (int r = 0; r < 16; ++r) {
                const int d = mt * 32 + (r & 3) + ((r >> 2) * 8) + g * 4;
                ep[q * 65 + d] = oacc[mt][r] * inv;
            }
    }
    __syncthreads();

    const size_t obase = (size_t)(b * S_LEN + qt * 128) * D_MODEL + h * DHEAD;
    for (int i = tid; i < 128 * 16; i += 256) {
        const int rloc = i >> 4, G = i & 15;
        const float* src = reinterpret_cast<float*>(lds) + (rloc >> 5) * 2080 + (rloc & 31) * 65 + G * 4;
        const size_t o = obase + (size_t)rloc * D_MODEL + perm4(G) * 4;
        bf16x4v hv;
#pragma unroll
        for (int j = 0; j < 4; ++j) hv[j] = (__bf16)src[j];
        *reinterpret_cast<bf16x4v*>(Ahi + o) = hv;
    }
}

// ---------------- launch ----------------
extern "C" void kernel_launch(void* const* d_in, const int* in_sizes, int n_in,
                              void* d_out, int out_size, void* d_ws, size_t ws_size,
                              hipStream_t stream)
{
    const float* query = (const float*)d_in[0];
    const float* value = (const float*)d_in[1];
    const float* Wq    = (const float*)d_in[2];
    const float* bq    = (const float*)d_in[3];
    const float* Wk    = (const float*)d_in[4];
    const float* bk    = (const float*)d_in[5];
    const float* Wv    = (const float*)d_in[6];
    const float* bv    = (const float*)d_in[7];
    const float* Wo    = (const float*)d_in[8];
    const float* bo    = (const float*)d_in[9];
    float* out = (float*)d_out;

    char* ws = (char*)d_ws;
    const size_t MB = 1024 * 1024;
    // 21.25 MB layout (proven-safe bound):
    //   [0,8)    Qin
    //   [8,16)   Qbf -> A (attention output aliases in place, same geometry)
    //   [16,18)  Wqt
    //   [18,18.5) Kbf   [18.5,19) Vt
    //   [19,21)  Wohit  [21,21.25) Wkvt
    __hip_bfloat16* Qin   = (__hip_bfloat16*)(ws);
    __hip_bfloat16* Qbf   = (__hip_bfloat16*)(ws + 8 * MB);
    __hip_bfloat16* Abuf  = (__hip_bfloat16*)(ws + 8 * MB);
    __hip_bfloat16* Wqt   = (__hip_bfloat16*)(ws + 16 * MB);
    __hip_bfloat16* Kbf   = (__hip_bfloat16*)(ws + 18 * MB);
    __hip_bfloat16* Vt    = (__hip_bfloat16*)(ws + 18 * MB + 524288);
    __hip_bfloat16* Wohit = (__hip_bfloat16*)(ws + 19 * MB);
    __hip_bfloat16* Wkvt  = (__hip_bfloat16*)(ws + 21 * MB);

    prep_all<<<dim3(8192), dim3(256), 0, stream>>>(
        query, Wq, Wo, Wk, Wv, Qin, Wqt, Wohit, Wkvt);

    qproj_projkv<<<dim3(320), dim3(512), 0, stream>>>(
        Qin, Wqt, bq, Qbf, value, Wkvt, bk, bv, Kbf, Vt);

    mqa_attn_mfma<<<dim3(S_LEN / 128, BATCH * NHEAD), dim3(256), 0, stream>>>(
        Qbf, Kbf, Vt, Abuf);

    gemm_oproj<<<dim3(8, 32), dim3(512), 0, stream>>>(
        Abuf, Wohit, bo, out);
}